// Round 1
// baseline (459.421 us; speedup 1.0000x reference)
//
#include <hip/hip_runtime.h>
#include <hip/hip_bf16.h>
#include <hip/hip_fp16.h>

#define SEQ 4096
#define DIM 1024
#define NH 16

typedef __attribute__((ext_vector_type(4))) float f32x4;
typedef __attribute__((ext_vector_type(8))) _Float16 half8;
typedef __attribute__((ext_vector_type(4))) _Float16 half4;

// ---------------- conversion kernels ----------------

__global__ __launch_bounds__(256) void conv_x(const float* __restrict__ x,
                                              _Float16* __restrict__ xh, int n) {
  int i = (blockIdx.x * 256 + threadIdx.x) * 4;
  if (i >= n) return;
  float4 v = *reinterpret_cast<const float4*>(x + i);
  half4 h;
  h[0] = (_Float16)v.x; h[1] = (_Float16)v.y;
  h[2] = (_Float16)v.z; h[3] = (_Float16)v.w;
  *reinterpret_cast<half4*>(xh + i) = h;
}

// W [K][N] fp32 row-major -> Wt [N][K] fp16 row-major
__global__ __launch_bounds__(256) void conv_wT(const float* __restrict__ W,
                                               _Float16* __restrict__ Wt) {
  __shared__ float t[32][33];
  int bx = blockIdx.x * 32;  // n block
  int by = blockIdx.y * 32;  // k block
  int tx = threadIdx.x & 31, ty = threadIdx.x >> 5;
#pragma unroll
  for (int i = 0; i < 4; i++)
    t[ty + i * 8][tx] = W[(by + ty + i * 8) * DIM + bx + tx];
  __syncthreads();
#pragma unroll
  for (int i = 0; i < 4; i++)
    Wt[(bx + ty + i * 8) * DIM + by + tx] = (_Float16)t[tx][ty + i * 8];
}

// ---------------- GEMM: C = A @ Bt^T + bias ----------------
// A: [M][K] fp16 row-major, Bt: [N][K] fp16 row-major.
// MODE 0: write fp16 head-major Q/K/V layout [n>>6][row][n&63]
// MODE 1: write fp32 row-major [row][col] (final output)
template <int MODE>
__global__ __launch_bounds__(256) void gemm_bt(const _Float16* __restrict__ A,
                                               const _Float16* __restrict__ Bt,
                                               const float* __restrict__ bias,
                                               void* __restrict__ outp,
                                               int M, int N, int Kd) {
  __shared__ __align__(16) _Float16 As[128][40];
  __shared__ __align__(16) _Float16 Bs[128][40];
  const int tid = threadIdx.x, lane = tid & 63, w = tid >> 6;
  const int wr = w >> 1, wc = w & 1;
  const int bm = blockIdx.x * 128, bn = blockIdx.y * 128;
  const int l15 = lane & 15, kb = (lane >> 4) * 8;
  const int srow = tid >> 2, scol = (tid & 3) * 8;
  f32x4 acc[4][4] = {};

  for (int k0 = 0; k0 < Kd; k0 += 32) {
    __syncthreads();
    *reinterpret_cast<uint4*>(&As[srow][scol]) =
        *reinterpret_cast<const uint4*>(&A[(bm + srow) * Kd + k0 + scol]);
    *reinterpret_cast<uint4*>(&As[64 + srow][scol]) =
        *reinterpret_cast<const uint4*>(&A[(bm + 64 + srow) * Kd + k0 + scol]);
    *reinterpret_cast<uint4*>(&Bs[srow][scol]) =
        *reinterpret_cast<const uint4*>(&Bt[(bn + srow) * Kd + k0 + scol]);
    *reinterpret_cast<uint4*>(&Bs[64 + srow][scol]) =
        *reinterpret_cast<const uint4*>(&Bt[(bn + 64 + srow) * Kd + k0 + scol]);
    __syncthreads();
    half8 af[4], bf[4];
#pragma unroll
    for (int i = 0; i < 4; i++)
      af[i] = *reinterpret_cast<const half8*>(&As[wr * 64 + i * 16 + l15][kb]);
#pragma unroll
    for (int i = 0; i < 4; i++)
      bf[i] = *reinterpret_cast<const half8*>(&Bs[wc * 64 + i * 16 + l15][kb]);
#pragma unroll
    for (int i = 0; i < 4; i++)
#pragma unroll
      for (int j = 0; j < 4; j++)
        acc[i][j] = __builtin_amdgcn_mfma_f32_16x16x32_f16(af[i], bf[j], acc[i][j], 0, 0, 0);
  }

#pragma unroll
  for (int i = 0; i < 4; i++)
#pragma unroll
    for (int j = 0; j < 4; j++)
#pragma unroll
      for (int r = 0; r < 4; r++) {
        int row = bm + wr * 64 + i * 16 + (lane >> 4) * 4 + r;
        int col = bn + wc * 64 + j * 16 + l15;
        float vv = acc[i][j][r] + bias[col];
        if (MODE == 0) {
          _Float16* O = (_Float16*)outp;
          O[(((col >> 6) * SEQ) + row) * 64 + (col & 63)] = (_Float16)vv;
        } else {
          float* O = (float*)outp;
          O[row * N + col] = vv;
        }
      }
}

// ---------------- flash attention ----------------
// Q,K,V: fp16 [h][s][64]; Og: fp16 [s][h*64+dv]
__global__ __launch_bounds__(256) void attn_fwd(const _Float16* __restrict__ Q,
                                                const _Float16* __restrict__ Kh,
                                                const _Float16* __restrict__ Vh,
                                                _Float16* __restrict__ Og) {
  __shared__ __align__(16) _Float16 Ks[64][72];
  __shared__ __align__(16) _Float16 Vt[64][72];   // Vt[dv][key]
  __shared__ __align__(16) _Float16 Ps[4][16][72];
  const int h = blockIdx.y;
  const int q0 = blockIdx.x * 64;
  const int tid = threadIdx.x, lane = tid & 63, w = tid >> 6;
  const int l15 = lane & 15, kb = (lane >> 4) * 8;

  const int qrow = q0 + w * 16 + l15;
  const _Float16* qp = Q + (h * SEQ + qrow) * 64;
  half8 qf0 = *reinterpret_cast<const half8*>(qp + kb);
  half8 qf1 = *reinterpret_cast<const half8*>(qp + 32 + kb);

  f32x4 o[4] = {};
  float mrow[4], lrow[4];
#pragma unroll
  for (int r = 0; r < 4; r++) { mrow[r] = -1e30f; lrow[r] = 0.f; }

  const int skey = tid >> 3, sd8 = (tid & 7) * 8;

  for (int kt = 0; kt < SEQ / 64; ++kt) {
    __syncthreads();
#pragma unroll
    for (int p = 0; p < 2; p++) {
      int kk = skey + p * 32;
      const _Float16* kp = Kh + ((h * SEQ) + kt * 64 + kk) * 64 + sd8;
      *reinterpret_cast<uint4*>(&Ks[kk][sd8]) = *reinterpret_cast<const uint4*>(kp);
      half8 vv = *reinterpret_cast<const half8*>(Vh + ((h * SEQ) + kt * 64 + kk) * 64 + sd8);
#pragma unroll
      for (int j = 0; j < 8; j++) Vt[sd8 + j][kk] = vv[j];
    }
    __syncthreads();

    // S = Q K^T
    f32x4 sf[4] = {};
#pragma unroll
    for (int f = 0; f < 4; f++) {
      half8 kf0 = *reinterpret_cast<const half8*>(&Ks[f * 16 + l15][kb]);
      half8 kf1 = *reinterpret_cast<const half8*>(&Ks[f * 16 + l15][32 + kb]);
      sf[f] = __builtin_amdgcn_mfma_f32_16x16x32_f16(qf0, kf0, sf[f], 0, 0, 0);
      sf[f] = __builtin_amdgcn_mfma_f32_16x16x32_f16(qf1, kf1, sf[f], 0, 0, 0);
    }
#pragma unroll
    for (int f = 0; f < 4; f++) sf[f] *= 0.125f;  // 1/sqrt(DK)

    // online softmax: rows live on 16-lane groups, 4 rows/lane (reg r)
    float pm[4];
#pragma unroll
    for (int r = 0; r < 4; r++)
      pm[r] = fmaxf(fmaxf(sf[0][r], sf[1][r]), fmaxf(sf[2][r], sf[3][r]));
#pragma unroll
    for (int msk = 1; msk < 16; msk <<= 1)
#pragma unroll
      for (int r = 0; r < 4; r++) pm[r] = fmaxf(pm[r], __shfl_xor(pm[r], msk, 64));

    float alpha[4], rs[4];
#pragma unroll
    for (int r = 0; r < 4; r++) {
      float mn = fmaxf(mrow[r], pm[r]);
      alpha[r] = __expf(mrow[r] - mn);
      mrow[r] = mn;
      rs[r] = 0.f;
    }
#pragma unroll
    for (int f = 0; f < 4; f++)
#pragma unroll
      for (int r = 0; r < 4; r++) {
        float p = __expf(sf[f][r] - mrow[r]);
        rs[r] += p;
        Ps[w][(lane >> 4) * 4 + r][f * 16 + l15] = (_Float16)p;
      }
#pragma unroll
    for (int msk = 1; msk < 16; msk <<= 1)
#pragma unroll
      for (int r = 0; r < 4; r++) rs[r] += __shfl_xor(rs[r], msk, 64);
#pragma unroll
    for (int r = 0; r < 4; r++) lrow[r] = lrow[r] * alpha[r] + rs[r];
#pragma unroll
    for (int f = 0; f < 4; f++)
#pragma unroll
      for (int r = 0; r < 4; r++) o[f][r] *= alpha[r];

    __syncthreads();  // make P visible for fragment-layout re-read (wave-private but keep ordering safe)

    // O += P V
    half8 pa0 = *reinterpret_cast<const half8*>(&Ps[w][l15][kb]);
    half8 pa1 = *reinterpret_cast<const half8*>(&Ps[w][l15][32 + kb]);
#pragma unroll
    for (int f = 0; f < 4; f++) {
      half8 vb0 = *reinterpret_cast<const half8*>(&Vt[f * 16 + l15][kb]);
      half8 vb1 = *reinterpret_cast<const half8*>(&Vt[f * 16 + l15][32 + kb]);
      o[f] = __builtin_amdgcn_mfma_f32_16x16x32_f16(pa0, vb0, o[f], 0, 0, 0);
      o[f] = __builtin_amdgcn_mfma_f32_16x16x32_f16(pa1, vb1, o[f], 0, 0, 0);
    }
  }

#pragma unroll
  for (int f = 0; f < 4; f++)
#pragma unroll
    for (int r = 0; r < 4; r++) {
      int row = q0 + w * 16 + (lane >> 4) * 4 + r;
      int dv = f * 16 + l15;
      Og[row * DIM + h * 64 + dv] = (_Float16)(o[f][r] / lrow[r]);
    }
}

// ---------------- launch ----------------

extern "C" void kernel_launch(void* const* d_in, const int* in_sizes, int n_in,
                              void* d_out, int out_size, void* d_ws, size_t ws_size,
                              hipStream_t stream) {
  const float* x  = (const float*)d_in[0];
  const float* Wq = (const float*)d_in[1];
  const float* bq = (const float*)d_in[2];
  const float* Wk = (const float*)d_in[3];
  const float* bk = (const float*)d_in[4];
  const float* Wv = (const float*)d_in[5];
  const float* bv = (const float*)d_in[6];
  const float* Wo = (const float*)d_in[7];
  const float* bo = (const float*)d_in[8];

  char* ws = (char*)d_ws;
  _Float16* xh  = (_Float16*)ws;                         // SEQ*DIM
  _Float16* WqT = (_Float16*)(ws + (size_t)SEQ * DIM * 2);
  _Float16* WkT = WqT + DIM * DIM;
  _Float16* WvT = WkT + DIM * DIM;
  _Float16* WoT = WvT + DIM * DIM;
  _Float16* Qd  = WoT + DIM * DIM;                       // [16][SEQ][64]
  _Float16* Kd  = Qd + (size_t)SEQ * DIM;
  _Float16* Vd  = Kd + (size_t)SEQ * DIM;
  _Float16* Od  = Vd + (size_t)SEQ * DIM;                // [SEQ][DIM]

  conv_x<<<(SEQ * DIM) / 1024, 256, 0, stream>>>(x, xh, SEQ * DIM);
  dim3 tg(32, 32);
  conv_wT<<<tg, 256, 0, stream>>>(Wq, WqT);
  conv_wT<<<tg, 256, 0, stream>>>(Wk, WkT);
  conv_wT<<<tg, 256, 0, stream>>>(Wv, WvT);
  conv_wT<<<tg, 256, 0, stream>>>(Wo, WoT);

  dim3 gp(SEQ / 128, DIM / 128);
  gemm_bt<0><<<gp, 256, 0, stream>>>(xh, WqT, bq, (void*)Qd, SEQ, DIM, DIM);
  gemm_bt<0><<<gp, 256, 0, stream>>>(xh, WkT, bk, (void*)Kd, SEQ, DIM, DIM);
  gemm_bt<0><<<gp, 256, 0, stream>>>(xh, WvT, bv, (void*)Vd, SEQ, DIM, DIM);

  dim3 ga(SEQ / 64, NH);
  attn_fwd<<<ga, 256, 0, stream>>>(Qd, Kd, Vd, Od);

  gemm_bt<1><<<gp, 256, 0, stream>>>(Od, WoT, bo, d_out, SEQ, DIM, DIM);
}

// Round 2
// 280.510 us; speedup vs baseline: 1.6378x; 1.6378x over previous
//
#include <hip/hip_runtime.h>
#include <hip/hip_bf16.h>
#include <hip/hip_fp16.h>

#define SEQ 4096
#define DIM 1024
#define NH 16

typedef __attribute__((ext_vector_type(4))) float f32x4;
typedef __attribute__((ext_vector_type(8))) _Float16 half8;
typedef __attribute__((ext_vector_type(4))) _Float16 half4;

// ---------------- conversion kernels ----------------

__global__ __launch_bounds__(256) void conv_x(const float* __restrict__ x,
                                              _Float16* __restrict__ xh, int n) {
  int i = (blockIdx.x * 256 + threadIdx.x) * 4;
  if (i >= n) return;
  float4 v = *reinterpret_cast<const float4*>(x + i);
  half4 h;
  h[0] = (_Float16)v.x; h[1] = (_Float16)v.y;
  h[2] = (_Float16)v.z; h[3] = (_Float16)v.w;
  *reinterpret_cast<half4*>(xh + i) = h;
}

// W [K][N] fp32 row-major -> Wt [N][K] fp16 row-major
__global__ __launch_bounds__(256) void conv_wT(const float* __restrict__ W,
                                               _Float16* __restrict__ Wt) {
  __shared__ float t[32][33];
  int bx = blockIdx.x * 32;  // n block
  int by = blockIdx.y * 32;  // k block
  int tx = threadIdx.x & 31, ty = threadIdx.x >> 5;
#pragma unroll
  for (int i = 0; i < 4; i++)
    t[ty + i * 8][tx] = W[(by + ty + i * 8) * DIM + bx + tx];
  __syncthreads();
#pragma unroll
  for (int i = 0; i < 4; i++)
    Wt[(bx + ty + i * 8) * DIM + by + tx] = (_Float16)t[tx][ty + i * 8];
}

// ---------------- GEMM: C = A @ Bt^T + bias ----------------
// A: [M][K] fp16 row-major, Bt: [N][K] fp16 row-major.
// MODE 0: write fp16 head-major layout [n>>6][row][n&63]   (Q, K)
// MODE 1: write fp32 row-major [row][col]                  (final output)
// MODE 2: write fp16 transposed [col][row]                 (V -> [h][dv][seq])
template <int MODE>
__global__ __launch_bounds__(256) void gemm_bt(const _Float16* __restrict__ A,
                                               const _Float16* __restrict__ Bt,
                                               const float* __restrict__ bias,
                                               void* __restrict__ outp,
                                               int M, int N, int Kd) {
  __shared__ __align__(16) _Float16 As[128][40];
  __shared__ __align__(16) _Float16 Bs[128][40];
  const int tid = threadIdx.x, lane = tid & 63, w = tid >> 6;
  const int wr = w >> 1, wc = w & 1;
  const int bm = blockIdx.x * 128, bn = blockIdx.y * 128;
  const int l15 = lane & 15, kb = (lane >> 4) * 8;
  const int srow = tid >> 2, scol = (tid & 3) * 8;
  f32x4 acc[4][4] = {};

  for (int k0 = 0; k0 < Kd; k0 += 32) {
    __syncthreads();
    *reinterpret_cast<uint4*>(&As[srow][scol]) =
        *reinterpret_cast<const uint4*>(&A[(bm + srow) * Kd + k0 + scol]);
    *reinterpret_cast<uint4*>(&As[64 + srow][scol]) =
        *reinterpret_cast<const uint4*>(&A[(bm + 64 + srow) * Kd + k0 + scol]);
    *reinterpret_cast<uint4*>(&Bs[srow][scol]) =
        *reinterpret_cast<const uint4*>(&Bt[(bn + srow) * Kd + k0 + scol]);
    *reinterpret_cast<uint4*>(&Bs[64 + srow][scol]) =
        *reinterpret_cast<const uint4*>(&Bt[(bn + 64 + srow) * Kd + k0 + scol]);
    __syncthreads();
    half8 af[4], bf[4];
#pragma unroll
    for (int i = 0; i < 4; i++)
      af[i] = *reinterpret_cast<const half8*>(&As[wr * 64 + i * 16 + l15][kb]);
#pragma unroll
    for (int i = 0; i < 4; i++)
      bf[i] = *reinterpret_cast<const half8*>(&Bs[wc * 64 + i * 16 + l15][kb]);
#pragma unroll
    for (int i = 0; i < 4; i++)
#pragma unroll
      for (int j = 0; j < 4; j++)
        acc[i][j] = __builtin_amdgcn_mfma_f32_16x16x32_f16(af[i], bf[j], acc[i][j], 0, 0, 0);
  }

#pragma unroll
  for (int i = 0; i < 4; i++)
#pragma unroll
    for (int j = 0; j < 4; j++) {
      const int row0 = bm + wr * 64 + i * 16 + (lane >> 4) * 4;
      const int col = bn + wc * 64 + j * 16 + l15;
      if (MODE == 2) {
        half4 hv;
#pragma unroll
        for (int r = 0; r < 4; r++) hv[r] = (_Float16)(acc[i][j][r] + bias[col]);
        *reinterpret_cast<half4*>(&((_Float16*)outp)[(size_t)col * M + row0]) = hv;
      } else {
#pragma unroll
        for (int r = 0; r < 4; r++) {
          float vv = acc[i][j][r] + bias[col];
          if (MODE == 0) {
            _Float16* O = (_Float16*)outp;
            O[(((col >> 6) * SEQ) + row0 + r) * 64 + (col & 63)] = (_Float16)vv;
          } else {
            float* O = (float*)outp;
            O[(row0 + r) * N + col] = vv;
          }
        }
      }
    }
}

// ---------------- flash attention (swapped-operand, S^T in regs) ----------------
// Q,K: fp16 [h][s][64]; Vt_g: fp16 [h*64+dv][s]; Og: fp16 [s][DIM]
__global__ __launch_bounds__(256) void attn_fwd(const _Float16* __restrict__ Q,
                                                const _Float16* __restrict__ Kh,
                                                const _Float16* __restrict__ Vt_g,
                                                _Float16* __restrict__ Og) {
  __shared__ __align__(16) _Float16 Ks[64][72];        // [key][d]
  __shared__ __align__(16) _Float16 Vs[64][72];        // [dv][key]
  __shared__ __align__(16) _Float16 Ps[4][16][72];     // [wave][q][key]
  const int h = blockIdx.y;
  const int q0 = blockIdx.x * 64;
  const int tid = threadIdx.x, lane = tid & 63, w = tid >> 6;
  const int l15 = lane & 15, g = lane >> 4, kb = g * 8;

  const int qrow = q0 + w * 16 + l15;
  const _Float16* qp = Q + ((size_t)h * SEQ + qrow) * 64;
  half8 qf0 = *reinterpret_cast<const half8*>(qp + kb);
  half8 qf1 = *reinterpret_cast<const half8*>(qp + 32 + kb);
#pragma unroll
  for (int e = 0; e < 8; e++) {  // fold 1/sqrt(64) into Q (exact pow2)
    qf0[e] = qf0[e] * (_Float16)0.125f;
    qf1[e] = qf1[e] * (_Float16)0.125f;
  }

  f32x4 o[4] = {};
  float m = -1e30f, l = 0.f;

  const int srow = tid >> 3, sc8 = (tid & 7) * 8;
  const _Float16* kbase = Kh + (size_t)h * SEQ * 64;
  const _Float16* vbase = Vt_g + (size_t)h * 64 * SEQ;

  for (int kt = 0; kt < SEQ / 64; ++kt) {
    __syncthreads();
#pragma unroll
    for (int p = 0; p < 2; p++) {
      int rr = srow + p * 32;
      *reinterpret_cast<uint4*>(&Ks[rr][sc8]) =
          *reinterpret_cast<const uint4*>(kbase + (size_t)(kt * 64 + rr) * 64 + sc8);
      *reinterpret_cast<uint4*>(&Vs[rr][sc8]) =
          *reinterpret_cast<const uint4*>(vbase + (size_t)rr * SEQ + kt * 64 + sc8);
    }
    __syncthreads();

    // S^T[key][q] = K Q^T   (A = K fragment, B = Q fragment)
    f32x4 sf[4] = {};
#pragma unroll
    for (int f = 0; f < 4; f++) {
      half8 kf0 = *reinterpret_cast<const half8*>(&Ks[f * 16 + l15][kb]);
      half8 kf1 = *reinterpret_cast<const half8*>(&Ks[f * 16 + l15][32 + kb]);
      sf[f] = __builtin_amdgcn_mfma_f32_16x16x32_f16(kf0, qf0, sf[f], 0, 0, 0);
      sf[f] = __builtin_amdgcn_mfma_f32_16x16x32_f16(kf1, qf1, sf[f], 0, 0, 0);
    }

    // online softmax — one query per lane (q = l15), 16 key-values in regs
    float pm = sf[0][0];
#pragma unroll
    for (int f = 0; f < 4; f++)
#pragma unroll
      for (int r = 0; r < 4; r++) pm = fmaxf(pm, sf[f][r]);
    pm = fmaxf(pm, __shfl_xor(pm, 16, 64));
    pm = fmaxf(pm, __shfl_xor(pm, 32, 64));
    float mn = fmaxf(m, pm);
    float alpha = __expf(m - mn);
    m = mn;
    float rs = 0.f;
    half4 ph[4];
#pragma unroll
    for (int f = 0; f < 4; f++)
#pragma unroll
      for (int r = 0; r < 4; r++) {
        float p = __expf(sf[f][r] - mn);
        rs += p;
        ph[f][r] = (_Float16)p;
      }
    rs += __shfl_xor(rs, 16, 64);
    rs += __shfl_xor(rs, 32, 64);
    l = l * alpha + rs;
#pragma unroll
    for (int f = 0; f < 4; f++) o[f] *= alpha;

    // P^T redistribution via wave-private LDS (vectorized, no barrier needed)
#pragma unroll
    for (int f = 0; f < 4; f++)
      *reinterpret_cast<half4*>(&Ps[w][l15][f * 16 + g * 4]) = ph[f];
    half8 pa0 = *reinterpret_cast<const half8*>(&Ps[w][l15][kb]);
    half8 pa1 = *reinterpret_cast<const half8*>(&Ps[w][l15][32 + kb]);

    // O^T[dv][q] += V^T P^T   (A = V^T fragment, B = P^T fragment)
#pragma unroll
    for (int f = 0; f < 4; f++) {
      half8 vf0 = *reinterpret_cast<const half8*>(&Vs[f * 16 + l15][kb]);
      half8 vf1 = *reinterpret_cast<const half8*>(&Vs[f * 16 + l15][32 + kb]);
      o[f] = __builtin_amdgcn_mfma_f32_16x16x32_f16(vf0, pa0, o[f], 0, 0, 0);
      o[f] = __builtin_amdgcn_mfma_f32_16x16x32_f16(vf1, pa1, o[f], 0, 0, 0);
    }
  }

  float rinv = 1.f / l;
#pragma unroll
  for (int f = 0; f < 4; f++) {
    half4 hv;
#pragma unroll
    for (int r = 0; r < 4; r++) hv[r] = (_Float16)(o[f][r] * rinv);
    *reinterpret_cast<half4*>(&Og[(size_t)qrow * DIM + h * 64 + f * 16 + g * 4]) = hv;
  }
}

// ---------------- launch ----------------

extern "C" void kernel_launch(void* const* d_in, const int* in_sizes, int n_in,
                              void* d_out, int out_size, void* d_ws, size_t ws_size,
                              hipStream_t stream) {
  const float* x  = (const float*)d_in[0];
  const float* Wq = (const float*)d_in[1];
  const float* bq = (const float*)d_in[2];
  const float* Wk = (const float*)d_in[3];
  const float* bk = (const float*)d_in[4];
  const float* Wv = (const float*)d_in[5];
  const float* bv = (const float*)d_in[6];
  const float* Wo = (const float*)d_in[7];
  const float* bo = (const float*)d_in[8];

  char* ws = (char*)d_ws;
  _Float16* xh  = (_Float16*)ws;                         // [SEQ][DIM]
  _Float16* WqT = (_Float16*)(ws + (size_t)SEQ * DIM * 2);
  _Float16* WkT = WqT + DIM * DIM;
  _Float16* WvT = WkT + DIM * DIM;
  _Float16* WoT = WvT + DIM * DIM;
  _Float16* Qd  = WoT + DIM * DIM;                       // [16][SEQ][64]
  _Float16* Kd  = Qd + (size_t)SEQ * DIM;                // [16][SEQ][64]
  _Float16* Vd  = Kd + (size_t)SEQ * DIM;                // [DIM][SEQ]  (V^T)
  _Float16* Od  = Vd + (size_t)SEQ * DIM;                // [SEQ][DIM]

  conv_x<<<(SEQ * DIM) / 1024, 256, 0, stream>>>(x, xh, SEQ * DIM);
  dim3 tg(32, 32);
  conv_wT<<<tg, 256, 0, stream>>>(Wq, WqT);
  conv_wT<<<tg, 256, 0, stream>>>(Wk, WkT);
  conv_wT<<<tg, 256, 0, stream>>>(Wv, WvT);
  conv_wT<<<tg, 256, 0, stream>>>(Wo, WoT);

  dim3 gp(SEQ / 128, DIM / 128);
  gemm_bt<0><<<gp, 256, 0, stream>>>(xh, WqT, bq, (void*)Qd, SEQ, DIM, DIM);
  gemm_bt<0><<<gp, 256, 0, stream>>>(xh, WkT, bk, (void*)Kd, SEQ, DIM, DIM);
  gemm_bt<2><<<gp, 256, 0, stream>>>(xh, WvT, bv, (void*)Vd, SEQ, DIM, DIM);

  dim3 ga(SEQ / 64, NH);
  attn_fwd<<<ga, 256, 0, stream>>>(Qd, Kd, Vd, Od);

  gemm_bt<1><<<gp, 256, 0, stream>>>(Od, WoT, bo, d_out, SEQ, DIM, DIM);
}

// Round 3
// 223.595 us; speedup vs baseline: 2.0547x; 1.2545x over previous
//
#include <hip/hip_runtime.h>
#include <hip/hip_bf16.h>
#include <hip/hip_fp16.h>

#define SEQ 4096
#define DIM 1024
#define NH 16

typedef __attribute__((ext_vector_type(4))) float f32x4;
typedef __attribute__((ext_vector_type(8))) _Float16 half8;
typedef __attribute__((ext_vector_type(4))) _Float16 half4;

#if __has_builtin(__builtin_amdgcn_exp2f)
#define EXP2(x) __builtin_amdgcn_exp2f(x)
#else
#define EXP2(x) exp2f(x)
#endif

// ---------------- conversion kernels ----------------

__global__ __launch_bounds__(256) void conv_x(const float* __restrict__ x,
                                              _Float16* __restrict__ xh, int n) {
  int i = (blockIdx.x * 256 + threadIdx.x) * 4;
  if (i >= n) return;
  float4 v = *reinterpret_cast<const float4*>(x + i);
  half4 h;
  h[0] = (_Float16)v.x; h[1] = (_Float16)v.y;
  h[2] = (_Float16)v.z; h[3] = (_Float16)v.w;
  *reinterpret_cast<half4*>(xh + i) = h;
}

// W [K][N] fp32 row-major -> Wt [N][K] fp16 row-major
__global__ __launch_bounds__(256) void conv_wT(const float* __restrict__ W,
                                               _Float16* __restrict__ Wt) {
  __shared__ float t[32][33];
  int bx = blockIdx.x * 32;  // n block
  int by = blockIdx.y * 32;  // k block
  int tx = threadIdx.x & 31, ty = threadIdx.x >> 5;
#pragma unroll
  for (int i = 0; i < 4; i++)
    t[ty + i * 8][tx] = W[(by + ty + i * 8) * DIM + bx + tx];
  __syncthreads();
#pragma unroll
  for (int i = 0; i < 4; i++)
    Wt[(bx + ty + i * 8) * DIM + by + tx] = (_Float16)t[tx][ty + i * 8];
}

// ---------------- GEMM: C = A @ Bt^T + bias ----------------
// Tile 64(M) x 128(N), BK=64, 4 waves (each wave: 64M x 32N).
// A: [M][K] fp16 row-major, Bt: [N][K] fp16 row-major.
// MODE 0: write fp16 head-major layout [n>>6][row][n&63]   (Q, K)
// MODE 1: write fp32 row-major [row][col]                  (final output)
// MODE 2: write fp16 transposed [col][row]                 (V -> [h][dv][seq])
template <int MODE>
__global__ __launch_bounds__(256) void gemm_bt(const _Float16* __restrict__ A,
                                               const _Float16* __restrict__ Bt,
                                               const float* __restrict__ bias,
                                               void* __restrict__ outp,
                                               int M, int N, int Kd) {
  __shared__ __align__(16) _Float16 As[64][72];
  __shared__ __align__(16) _Float16 Bs[128][72];
  const int tid = threadIdx.x, lane = tid & 63, w = tid >> 6;
  const int bm = blockIdx.x * 64, bn = blockIdx.y * 128;
  const int l15 = lane & 15, g = lane >> 4, kb = g * 8;
  const int sra = tid >> 2, sca = (tid & 3) * 16;  // A stage: 32B/thread
  const int srb = tid >> 1, scb = (tid & 1) * 32;  // B stage: 64B/thread
  f32x4 acc[4][2] = {};

  uint4 ar0, ar1, br0, br1, br2, br3;
  auto LOADT = [&](int k0) {
    const _Float16* ap = A + (size_t)(bm + sra) * Kd + k0 + sca;
    ar0 = *reinterpret_cast<const uint4*>(ap);
    ar1 = *reinterpret_cast<const uint4*>(ap + 8);
    const _Float16* bp = Bt + (size_t)(bn + srb) * Kd + k0 + scb;
    br0 = *reinterpret_cast<const uint4*>(bp);
    br1 = *reinterpret_cast<const uint4*>(bp + 8);
    br2 = *reinterpret_cast<const uint4*>(bp + 16);
    br3 = *reinterpret_cast<const uint4*>(bp + 24);
  };

  LOADT(0);
  for (int k0 = 0; k0 < Kd; k0 += 64) {
    __syncthreads();
    *reinterpret_cast<uint4*>(&As[sra][sca]) = ar0;
    *reinterpret_cast<uint4*>(&As[sra][sca + 8]) = ar1;
    *reinterpret_cast<uint4*>(&Bs[srb][scb]) = br0;
    *reinterpret_cast<uint4*>(&Bs[srb][scb + 8]) = br1;
    *reinterpret_cast<uint4*>(&Bs[srb][scb + 16]) = br2;
    *reinterpret_cast<uint4*>(&Bs[srb][scb + 24]) = br3;
    __syncthreads();
    if (k0 + 64 < Kd) LOADT(k0 + 64);
#pragma unroll
    for (int kk = 0; kk < 64; kk += 32) {
      half8 af[4], bf[2];
#pragma unroll
      for (int i = 0; i < 4; i++)
        af[i] = *reinterpret_cast<const half8*>(&As[i * 16 + l15][kk + kb]);
#pragma unroll
      for (int j = 0; j < 2; j++)
        bf[j] = *reinterpret_cast<const half8*>(&Bs[w * 32 + j * 16 + l15][kk + kb]);
#pragma unroll
      for (int i = 0; i < 4; i++)
#pragma unroll
        for (int j = 0; j < 2; j++)
          acc[i][j] = __builtin_amdgcn_mfma_f32_16x16x32_f16(af[i], bf[j], acc[i][j], 0, 0, 0);
    }
  }

#pragma unroll
  for (int i = 0; i < 4; i++)
#pragma unroll
    for (int j = 0; j < 2; j++) {
      const int row0 = bm + i * 16 + g * 4;
      const int col = bn + w * 32 + j * 16 + l15;
      if (MODE == 2) {
        half4 hv;
#pragma unroll
        for (int r = 0; r < 4; r++) hv[r] = (_Float16)(acc[i][j][r] + bias[col]);
        *reinterpret_cast<half4*>(&((_Float16*)outp)[(size_t)col * M + row0]) = hv;
      } else {
#pragma unroll
        for (int r = 0; r < 4; r++) {
          float vv = acc[i][j][r] + bias[col];
          if (MODE == 0) {
            _Float16* O = (_Float16*)outp;
            O[(((col >> 6) * SEQ) + row0 + r) * 64 + (col & 63)] = (_Float16)vv;
          } else {
            float* O = (float*)outp;
            O[(size_t)(row0 + r) * N + col] = vv;
          }
        }
      }
    }
}

// ---------------- flash attention (swapped-operand, S^T in regs) ----------------
// Q,K: fp16 [h][s][64]; Vt_g: fp16 [h*64+dv][s]; Og: fp16 [s][DIM]
__global__ __launch_bounds__(256) void attn_fwd(const _Float16* __restrict__ Q,
                                                const _Float16* __restrict__ Kh,
                                                const _Float16* __restrict__ Vt_g,
                                                _Float16* __restrict__ Og) {
  __shared__ __align__(16) _Float16 Ks[64][72];        // [key][d]
  __shared__ __align__(16) _Float16 Vs[64][72];        // [dv][key]
  __shared__ __align__(16) _Float16 Ps[4][16][72];     // [wave][q][key]
  const int h = blockIdx.y;
  const int q0 = blockIdx.x * 64;
  const int tid = threadIdx.x, lane = tid & 63, w = tid >> 6;
  const int l15 = lane & 15, g = lane >> 4, kb = g * 8;

  // exp(s*0.125) == exp2(s*C), C = 0.125*log2(e); Q stays exact fp16
  const float C = 0.18033688f;

  const int qrow = q0 + w * 16 + l15;
  const _Float16* qp = Q + ((size_t)h * SEQ + qrow) * 64;
  const half8 qf0 = *reinterpret_cast<const half8*>(qp + kb);
  const half8 qf1 = *reinterpret_cast<const half8*>(qp + 32 + kb);

  f32x4 o[4] = {};
  float m = -1e30f, l = 0.f;
  float negm2 = 1e30f * C;  // -m*C

  const int srow = tid >> 3, sc8 = (tid & 7) * 8;
  const _Float16* kbase = Kh + (size_t)h * SEQ * 64;
  const _Float16* vbase = Vt_g + (size_t)h * 64 * SEQ;

  uint4 kr0, kr1, vr0, vr1;
  auto LOADKV = [&](int kt2) {
    const _Float16* kp = kbase + (size_t)(kt2 * 64 + srow) * 64 + sc8;
    kr0 = *reinterpret_cast<const uint4*>(kp);
    kr1 = *reinterpret_cast<const uint4*>(kp + 32 * 64);
    const _Float16* vp = vbase + (size_t)srow * SEQ + kt2 * 64 + sc8;
    vr0 = *reinterpret_cast<const uint4*>(vp);
    vr1 = *reinterpret_cast<const uint4*>(vp + 32 * SEQ);
  };

  LOADKV(0);
  for (int kt = 0; kt < SEQ / 64; ++kt) {
    __syncthreads();  // A: previous tile's reads done, LDS writable
    *reinterpret_cast<uint4*>(&Ks[srow][sc8]) = kr0;
    *reinterpret_cast<uint4*>(&Ks[srow + 32][sc8]) = kr1;
    *reinterpret_cast<uint4*>(&Vs[srow][sc8]) = vr0;
    *reinterpret_cast<uint4*>(&Vs[srow + 32][sc8]) = vr1;
    __syncthreads();  // B: tile ready
    if (kt + 1 < SEQ / 64) LOADKV(kt + 1);  // async: consumed at next iter's ds_write

    // S^T[key][q] = K Q^T   (A = K fragment, B = Q fragment)
    f32x4 sf[4] = {};
    __builtin_amdgcn_s_setprio(1);
#pragma unroll
    for (int f = 0; f < 4; f++) {
      half8 kf0 = *reinterpret_cast<const half8*>(&Ks[f * 16 + l15][kb]);
      half8 kf1 = *reinterpret_cast<const half8*>(&Ks[f * 16 + l15][32 + kb]);
      sf[f] = __builtin_amdgcn_mfma_f32_16x16x32_f16(kf0, qf0, sf[f], 0, 0, 0);
      sf[f] = __builtin_amdgcn_mfma_f32_16x16x32_f16(kf1, qf1, sf[f], 0, 0, 0);
    }
    __builtin_amdgcn_s_setprio(0);

    // online softmax — one query per lane (q = l15), 16 keys in regs (raw units)
    float pm = fmaxf(fmaxf(fmaxf(sf[0][0], sf[0][1]), fmaxf(sf[0][2], sf[0][3])),
                     fmaxf(fmaxf(sf[1][0], sf[1][1]), fmaxf(sf[1][2], sf[1][3])));
    pm = fmaxf(pm, fmaxf(fmaxf(fmaxf(sf[2][0], sf[2][1]), fmaxf(sf[2][2], sf[2][3])),
                         fmaxf(fmaxf(sf[3][0], sf[3][1]), fmaxf(sf[3][2], sf[3][3]))));
    pm = fmaxf(pm, __shfl_xor(pm, 16, 64));
    pm = fmaxf(pm, __shfl_xor(pm, 32, 64));
    if (__any(pm > m + 64.f)) {  // defer-max: 64 raw = 8 in exp-units
      float mn = fmaxf(m, pm);
      float al = EXP2((m - mn) * C);
      m = mn;
      negm2 = -m * C;
      l *= al;
#pragma unroll
      for (int f = 0; f < 4; f++) o[f] *= al;
    }
    float rs = 0.f;
    half4 ph[4];
#pragma unroll
    for (int f = 0; f < 4; f++)
#pragma unroll
      for (int r = 0; r < 4; r++) {
        float p = EXP2(fmaf(sf[f][r], C, negm2));
        rs += p;
        ph[f][r] = (_Float16)p;
      }
    rs += __shfl_xor(rs, 16, 64);
    rs += __shfl_xor(rs, 32, 64);
    l += rs;

    // P^T redistribution via wave-private LDS (vectorized, in-order DS pipe)
#pragma unroll
    for (int f = 0; f < 4; f++)
      *reinterpret_cast<half4*>(&Ps[w][l15][f * 16 + g * 4]) = ph[f];
    half8 pa0 = *reinterpret_cast<const half8*>(&Ps[w][l15][kb]);
    half8 pa1 = *reinterpret_cast<const half8*>(&Ps[w][l15][32 + kb]);

    // O^T[dv][q] += V^T P^T   (A = V^T fragment, B = P^T fragment)
    __builtin_amdgcn_s_setprio(1);
#pragma unroll
    for (int f = 0; f < 4; f++) {
      half8 vf0 = *reinterpret_cast<const half8*>(&Vs[f * 16 + l15][kb]);
      half8 vf1 = *reinterpret_cast<const half8*>(&Vs[f * 16 + l15][32 + kb]);
      o[f] = __builtin_amdgcn_mfma_f32_16x16x32_f16(vf0, pa0, o[f], 0, 0, 0);
      o[f] = __builtin_amdgcn_mfma_f32_16x16x32_f16(vf1, pa1, o[f], 0, 0, 0);
    }
    __builtin_amdgcn_s_setprio(0);
  }

  float rinv = 1.f / l;
#pragma unroll
  for (int f = 0; f < 4; f++) {
    half4 hv;
#pragma unroll
    for (int r = 0; r < 4; r++) hv[r] = (_Float16)(o[f][r] * rinv);
    *reinterpret_cast<half4*>(&Og[(size_t)qrow * DIM + h * 64 + f * 16 + g * 4]) = hv;
  }
}

// ---------------- launch ----------------

extern "C" void kernel_launch(void* const* d_in, const int* in_sizes, int n_in,
                              void* d_out, int out_size, void* d_ws, size_t ws_size,
                              hipStream_t stream) {
  const float* x  = (const float*)d_in[0];
  const float* Wq = (const float*)d_in[1];
  const float* bq = (const float*)d_in[2];
  const float* Wk = (const float*)d_in[3];
  const float* bk = (const float*)d_in[4];
  const float* Wv = (const float*)d_in[5];
  const float* bv = (const float*)d_in[6];
  const float* Wo = (const float*)d_in[7];
  const float* bo = (const float*)d_in[8];

  char* ws = (char*)d_ws;
  _Float16* xh  = (_Float16*)ws;                         // [SEQ][DIM]
  _Float16* WqT = (_Float16*)(ws + (size_t)SEQ * DIM * 2);
  _Float16* WkT = WqT + DIM * DIM;
  _Float16* WvT = WkT + DIM * DIM;
  _Float16* WoT = WvT + DIM * DIM;
  _Float16* Qd  = WoT + DIM * DIM;                       // [16][SEQ][64]
  _Float16* Kd  = Qd + (size_t)SEQ * DIM;                // [16][SEQ][64]
  _Float16* Vd  = Kd + (size_t)SEQ * DIM;                // [DIM][SEQ]  (V^T)
  _Float16* Od  = Vd + (size_t)SEQ * DIM;                // [SEQ][DIM]

  conv_x<<<(SEQ * DIM) / 1024, 256, 0, stream>>>(x, xh, SEQ * DIM);
  dim3 tg(32, 32);
  conv_wT<<<tg, 256, 0, stream>>>(Wq, WqT);
  conv_wT<<<tg, 256, 0, stream>>>(Wk, WkT);
  conv_wT<<<tg, 256, 0, stream>>>(Wv, WvT);
  conv_wT<<<tg, 256, 0, stream>>>(Wo, WoT);

  dim3 gp(SEQ / 64, DIM / 128);
  gemm_bt<0><<<gp, 256, 0, stream>>>(xh, WqT, bq, (void*)Qd, SEQ, DIM, DIM);
  gemm_bt<0><<<gp, 256, 0, stream>>>(xh, WkT, bk, (void*)Kd, SEQ, DIM, DIM);
  gemm_bt<2><<<gp, 256, 0, stream>>>(xh, WvT, bv, (void*)Vd, SEQ, DIM, DIM);

  dim3 ga(SEQ / 64, NH);
  attn_fwd<<<ga, 256, 0, stream>>>(Qd, Kd, Vd, Od);

  gemm_bt<1><<<gp, 256, 0, stream>>>(Od, WoT, bo, d_out, SEQ, DIM, DIM);
}

// Round 4
// 181.829 us; speedup vs baseline: 2.5267x; 1.2297x over previous
//
#include <hip/hip_runtime.h>
#include <hip/hip_bf16.h>
#include <hip/hip_fp16.h>

#define SEQ 4096
#define DIM 1024
#define NH 16

typedef __attribute__((ext_vector_type(4))) float f32x4;
typedef __attribute__((ext_vector_type(8))) _Float16 half8;
typedef __attribute__((ext_vector_type(4))) _Float16 half4;

#if __has_builtin(__builtin_amdgcn_exp2f)
#define EXP2(x) __builtin_amdgcn_exp2f(x)
#else
#define EXP2(x) exp2f(x)
#endif

// ---------------- conversion kernels ----------------

__global__ __launch_bounds__(256) void conv_x(const float* __restrict__ x,
                                              _Float16* __restrict__ xh, int n) {
  int i = (blockIdx.x * 256 + threadIdx.x) * 4;
  if (i >= n) return;
  float4 v = *reinterpret_cast<const float4*>(x + i);
  half4 h;
  h[0] = (_Float16)v.x; h[1] = (_Float16)v.y;
  h[2] = (_Float16)v.z; h[3] = (_Float16)v.w;
  *reinterpret_cast<half4*>(xh + i) = h;
}

// W [K][N] fp32 row-major -> Wt [N][K] fp16 row-major; z selects matrix
__global__ __launch_bounds__(256) void conv_wT4(const float* __restrict__ W0,
                                                const float* __restrict__ W1,
                                                const float* __restrict__ W2,
                                                const float* __restrict__ W3,
                                                _Float16* __restrict__ T0,
                                                _Float16* __restrict__ T1,
                                                _Float16* __restrict__ T2,
                                                _Float16* __restrict__ T3) {
  const float* W = blockIdx.z == 0 ? W0 : blockIdx.z == 1 ? W1 : blockIdx.z == 2 ? W2 : W3;
  _Float16* Wt = blockIdx.z == 0 ? T0 : blockIdx.z == 1 ? T1 : blockIdx.z == 2 ? T2 : T3;
  __shared__ float t[32][33];
  int bx = blockIdx.x * 32;  // n block
  int by = blockIdx.y * 32;  // k block
  int tx = threadIdx.x & 31, ty = threadIdx.x >> 5;
#pragma unroll
  for (int i = 0; i < 4; i++)
    t[ty + i * 8][tx] = W[(by + ty + i * 8) * DIM + bx + tx];
  __syncthreads();
#pragma unroll
  for (int i = 0; i < 4; i++)
    Wt[(bx + ty + i * 8) * DIM + by + tx] = (_Float16)t[tx][ty + i * 8];
}

// ---------------- GEMM core: C = A @ Bt^T + bias ----------------
// Tile 64(M) x 128(N), BK=64, 4 waves.
// MODE 0: fp16 head-major [n>>6][row][n&63]; MODE 1: fp32 [row][col]; MODE 2: fp16 [col][row]
template <int MODE>
__device__ __forceinline__ void gemm_body(const _Float16* __restrict__ A,
                                          const _Float16* __restrict__ Bt,
                                          const float* __restrict__ bias,
                                          void* __restrict__ outp,
                                          int M, int N, int Kd, int bmb, int bnb) {
  __shared__ __align__(16) _Float16 As[64][72];
  __shared__ __align__(16) _Float16 Bs[128][72];
  const int tid = threadIdx.x, lane = tid & 63, w = tid >> 6;
  const int bm = bmb * 64, bn = bnb * 128;
  const int l15 = lane & 15, g = lane >> 4, kb = g * 8;
  const int sra = tid >> 2, sca = (tid & 3) * 16;
  const int srb = tid >> 1, scb = (tid & 1) * 32;
  f32x4 acc[4][2] = {};

  uint4 ar0, ar1, br0, br1, br2, br3;
  auto LOADT = [&](int k0) {
    const _Float16* ap = A + (size_t)(bm + sra) * Kd + k0 + sca;
    ar0 = *reinterpret_cast<const uint4*>(ap);
    ar1 = *reinterpret_cast<const uint4*>(ap + 8);
    const _Float16* bp = Bt + (size_t)(bn + srb) * Kd + k0 + scb;
    br0 = *reinterpret_cast<const uint4*>(bp);
    br1 = *reinterpret_cast<const uint4*>(bp + 8);
    br2 = *reinterpret_cast<const uint4*>(bp + 16);
    br3 = *reinterpret_cast<const uint4*>(bp + 24);
  };

  LOADT(0);
  for (int k0 = 0; k0 < Kd; k0 += 64) {
    __syncthreads();
    *reinterpret_cast<uint4*>(&As[sra][sca]) = ar0;
    *reinterpret_cast<uint4*>(&As[sra][sca + 8]) = ar1;
    *reinterpret_cast<uint4*>(&Bs[srb][scb]) = br0;
    *reinterpret_cast<uint4*>(&Bs[srb][scb + 8]) = br1;
    *reinterpret_cast<uint4*>(&Bs[srb][scb + 16]) = br2;
    *reinterpret_cast<uint4*>(&Bs[srb][scb + 24]) = br3;
    __syncthreads();
    if (k0 + 64 < Kd) LOADT(k0 + 64);
#pragma unroll
    for (int kk = 0; kk < 64; kk += 32) {
      half8 af[4], bf[2];
#pragma unroll
      for (int i = 0; i < 4; i++)
        af[i] = *reinterpret_cast<const half8*>(&As[i * 16 + l15][kk + kb]);
#pragma unroll
      for (int j = 0; j < 2; j++)
        bf[j] = *reinterpret_cast<const half8*>(&Bs[w * 32 + j * 16 + l15][kk + kb]);
      __builtin_amdgcn_s_setprio(1);
#pragma unroll
      for (int i = 0; i < 4; i++)
#pragma unroll
        for (int j = 0; j < 2; j++)
          acc[i][j] = __builtin_amdgcn_mfma_f32_16x16x32_f16(af[i], bf[j], acc[i][j], 0, 0, 0);
      __builtin_amdgcn_s_setprio(0);
    }
  }

#pragma unroll
  for (int i = 0; i < 4; i++)
#pragma unroll
    for (int j = 0; j < 2; j++) {
      const int row0 = bm + i * 16 + g * 4;
      const int col = bn + w * 32 + j * 16 + l15;
      if (MODE == 2) {
        half4 hv;
#pragma unroll
        for (int r = 0; r < 4; r++) hv[r] = (_Float16)(acc[i][j][r] + bias[col]);
        *reinterpret_cast<half4*>(&((_Float16*)outp)[(size_t)col * M + row0]) = hv;
      } else {
#pragma unroll
        for (int r = 0; r < 4; r++) {
          float vv = acc[i][j][r] + bias[col];
          if (MODE == 0) {
            _Float16* O = (_Float16*)outp;
            O[(((col >> 6) * SEQ) + row0 + r) * 64 + (col & 63)] = (_Float16)vv;
          } else {
            float* O = (float*)outp;
            O[(size_t)(row0 + r) * N + col] = vv;
          }
        }
      }
    }
}

// fused QKV projection: z=0 -> Q (mode0), z=1 -> K (mode0), z=2 -> V (mode2)
__global__ __launch_bounds__(256) void gemm_qkv(const _Float16* __restrict__ A,
                                                const _Float16* __restrict__ WqT,
                                                const _Float16* __restrict__ WkT,
                                                const _Float16* __restrict__ WvT,
                                                const float* __restrict__ bq,
                                                const float* __restrict__ bk,
                                                const float* __restrict__ bv,
                                                _Float16* __restrict__ Qd,
                                                _Float16* __restrict__ Kd,
                                                _Float16* __restrict__ Vd) {
  if (blockIdx.z == 0)
    gemm_body<0>(A, WqT, bq, (void*)Qd, SEQ, DIM, DIM, blockIdx.x, blockIdx.y);
  else if (blockIdx.z == 1)
    gemm_body<0>(A, WkT, bk, (void*)Kd, SEQ, DIM, DIM, blockIdx.x, blockIdx.y);
  else
    gemm_body<2>(A, WvT, bv, (void*)Vd, SEQ, DIM, DIM, blockIdx.x, blockIdx.y);
}

__global__ __launch_bounds__(256) void gemm_out(const _Float16* __restrict__ A,
                                                const _Float16* __restrict__ Bt,
                                                const float* __restrict__ bias,
                                                float* __restrict__ out) {
  gemm_body<1>(A, Bt, bias, (void*)out, SEQ, DIM, DIM, blockIdx.x, blockIdx.y);
}

// ---------------- flash attention (swapped-operand, QBLK=32/wave) ----------------
// Q,K: fp16 [h][s][64]; Vt_g: fp16 [h*64+dv][s]; Og: fp16 [s][DIM]
__global__ __launch_bounds__(256) void attn_fwd(const _Float16* __restrict__ Q,
                                                const _Float16* __restrict__ Kh,
                                                const _Float16* __restrict__ Vt_g,
                                                _Float16* __restrict__ Og) {
  __shared__ __align__(16) _Float16 Ks[64][72];          // [key][d]
  __shared__ __align__(16) _Float16 Vs[64][72];          // [dv][key]
  __shared__ __align__(16) _Float16 Ps[4][2][16][72];    // [wave][sub][q][key]
  const int h = blockIdx.y;
  const int q0 = blockIdx.x * 128;
  const int tid = threadIdx.x, lane = tid & 63, w = tid >> 6;
  const int l15 = lane & 15, g = lane >> 4, kb = g * 8;

  // exp(s*0.125) == exp2(s*C), C = 0.125*log2(e)
  const float C = 0.18033688f;

  const int qrow = q0 + w * 32 + l15;  // sub0; sub1 = +16
  const _Float16* qp = Q + ((size_t)h * SEQ + qrow) * 64;
  half8 qf[2][2];
  qf[0][0] = *reinterpret_cast<const half8*>(qp + kb);
  qf[0][1] = *reinterpret_cast<const half8*>(qp + 32 + kb);
  qf[1][0] = *reinterpret_cast<const half8*>(qp + 16 * 64 + kb);
  qf[1][1] = *reinterpret_cast<const half8*>(qp + 16 * 64 + 32 + kb);

  f32x4 o[2][4] = {};
  float m[2] = {-1e30f, -1e30f};
  float lsum[2] = {0.f, 0.f};          // per-lane partial; reduced at end
  float negmC[2] = {1e30f, 1e30f};

  const int srow = tid >> 3, sc8 = (tid & 7) * 8;
  const _Float16* kbase = Kh + (size_t)h * SEQ * 64;
  const _Float16* vbase = Vt_g + (size_t)h * 64 * SEQ;

  uint4 kr0, kr1, vr0, vr1;
  auto LOADKV = [&](int kt2) {
    const _Float16* kp = kbase + (size_t)(kt2 * 64 + srow) * 64 + sc8;
    kr0 = *reinterpret_cast<const uint4*>(kp);
    kr1 = *reinterpret_cast<const uint4*>(kp + 32 * 64);
    const _Float16* vp = vbase + (size_t)srow * SEQ + kt2 * 64 + sc8;
    vr0 = *reinterpret_cast<const uint4*>(vp);
    vr1 = *reinterpret_cast<const uint4*>(vp + 32 * SEQ);
  };

  LOADKV(0);
  for (int kt = 0; kt < SEQ / 64; ++kt) {
    __syncthreads();  // previous tile's reads done
    *reinterpret_cast<uint4*>(&Ks[srow][sc8]) = kr0;
    *reinterpret_cast<uint4*>(&Ks[srow + 32][sc8]) = kr1;
    *reinterpret_cast<uint4*>(&Vs[srow][sc8]) = vr0;
    *reinterpret_cast<uint4*>(&Vs[srow + 32][sc8]) = vr1;
    __syncthreads();  // tile ready
    if (kt + 1 < SEQ / 64) LOADKV(kt + 1);  // latency hides under this tile

    // S^T[key][q] = K Q^T  (A = K frag, B = Q frag) — K frags reused by both subs
    f32x4 sf[2][4] = {};
    __builtin_amdgcn_s_setprio(1);
#pragma unroll
    for (int f = 0; f < 4; f++) {
      half8 kf0 = *reinterpret_cast<const half8*>(&Ks[f * 16 + l15][kb]);
      half8 kf1 = *reinterpret_cast<const half8*>(&Ks[f * 16 + l15][32 + kb]);
      sf[0][f] = __builtin_amdgcn_mfma_f32_16x16x32_f16(kf0, qf[0][0], sf[0][f], 0, 0, 0);
      sf[0][f] = __builtin_amdgcn_mfma_f32_16x16x32_f16(kf1, qf[0][1], sf[0][f], 0, 0, 0);
      sf[1][f] = __builtin_amdgcn_mfma_f32_16x16x32_f16(kf0, qf[1][0], sf[1][f], 0, 0, 0);
      sf[1][f] = __builtin_amdgcn_mfma_f32_16x16x32_f16(kf1, qf[1][1], sf[1][f], 0, 0, 0);
    }
    __builtin_amdgcn_s_setprio(0);

#pragma unroll
    for (int s = 0; s < 2; s++) {
      // local max (this lane's 16 keys); cross-lane reduce only if threshold hit
      float pm = fmaxf(fmaxf(fmaxf(sf[s][0][0], sf[s][0][1]), fmaxf(sf[s][0][2], sf[s][0][3])),
                       fmaxf(fmaxf(sf[s][1][0], sf[s][1][1]), fmaxf(sf[s][1][2], sf[s][1][3])));
      pm = fmaxf(pm, fmaxf(fmaxf(fmaxf(sf[s][2][0], sf[s][2][1]), fmaxf(sf[s][2][2], sf[s][2][3])),
                           fmaxf(fmaxf(sf[s][3][0], sf[s][3][1]), fmaxf(sf[s][3][2], sf[s][3][3]))));
      if (__any(pm > m[s] + 64.f)) {  // 64 raw = 8 exp-units
        pm = fmaxf(pm, __shfl_xor(pm, 16, 64));
        pm = fmaxf(pm, __shfl_xor(pm, 32, 64));
        float mn = fmaxf(m[s], pm);
        float al = EXP2((m[s] - mn) * C);
        m[s] = mn;
        negmC[s] = -mn * C;
        lsum[s] *= al;
#pragma unroll
        for (int f = 0; f < 4; f++) o[s][f] *= al;
      }
      half4 ph[4];
#pragma unroll
      for (int f = 0; f < 4; f++)
#pragma unroll
        for (int r = 0; r < 4; r++) {
          float p = EXP2(fmaf(sf[s][f][r], C, negmC[s]));
          lsum[s] += p;
          ph[f][r] = (_Float16)p;
        }
#pragma unroll
      for (int f = 0; f < 4; f++)
        *reinterpret_cast<half4*>(&Ps[w][s][l15][f * 16 + g * 4]) = ph[f];
    }

    half8 pa[2][2];
#pragma unroll
    for (int s = 0; s < 2; s++) {
      pa[s][0] = *reinterpret_cast<const half8*>(&Ps[w][s][l15][kb]);
      pa[s][1] = *reinterpret_cast<const half8*>(&Ps[w][s][l15][32 + kb]);
    }

    // O^T[dv][q] += V^T P^T — V frags reused by both subs
    __builtin_amdgcn_s_setprio(1);
#pragma unroll
    for (int f = 0; f < 4; f++) {
      half8 vf0 = *reinterpret_cast<const half8*>(&Vs[f * 16 + l15][kb]);
      half8 vf1 = *reinterpret_cast<const half8*>(&Vs[f * 16 + l15][32 + kb]);
      o[0][f] = __builtin_amdgcn_mfma_f32_16x16x32_f16(vf0, pa[0][0], o[0][f], 0, 0, 0);
      o[0][f] = __builtin_amdgcn_mfma_f32_16x16x32_f16(vf1, pa[0][1], o[0][f], 0, 0, 0);
      o[1][f] = __builtin_amdgcn_mfma_f32_16x16x32_f16(vf0, pa[1][0], o[1][f], 0, 0, 0);
      o[1][f] = __builtin_amdgcn_mfma_f32_16x16x32_f16(vf1, pa[1][1], o[1][f], 0, 0, 0);
    }
    __builtin_amdgcn_s_setprio(0);
  }

#pragma unroll
  for (int s = 0; s < 2; s++) {
    float ls = lsum[s];
    ls += __shfl_xor(ls, 16, 64);
    ls += __shfl_xor(ls, 32, 64);
    float rinv = 1.f / ls;
#pragma unroll
    for (int f = 0; f < 4; f++) {
      half4 hv;
#pragma unroll
      for (int r = 0; r < 4; r++) hv[r] = (_Float16)(o[s][f][r] * rinv);
      *reinterpret_cast<half4*>(
          &Og[(size_t)(qrow + 16 * s) * DIM + h * 64 + f * 16 + g * 4]) = hv;
    }
  }
}

// ---------------- launch ----------------

extern "C" void kernel_launch(void* const* d_in, const int* in_sizes, int n_in,
                              void* d_out, int out_size, void* d_ws, size_t ws_size,
                              hipStream_t stream) {
  const float* x  = (const float*)d_in[0];
  const float* Wq = (const float*)d_in[1];
  const float* bq = (const float*)d_in[2];
  const float* Wk = (const float*)d_in[3];
  const float* bk = (const float*)d_in[4];
  const float* Wv = (const float*)d_in[5];
  const float* bv = (const float*)d_in[6];
  const float* Wo = (const float*)d_in[7];
  const float* bo = (const float*)d_in[8];

  char* ws = (char*)d_ws;
  _Float16* xh  = (_Float16*)ws;                         // [SEQ][DIM]
  _Float16* WqT = (_Float16*)(ws + (size_t)SEQ * DIM * 2);
  _Float16* WkT = WqT + DIM * DIM;
  _Float16* WvT = WkT + DIM * DIM;
  _Float16* WoT = WvT + DIM * DIM;
  _Float16* Qd  = WoT + DIM * DIM;                       // [16][SEQ][64]
  _Float16* Kd  = Qd + (size_t)SEQ * DIM;                // [16][SEQ][64]
  _Float16* Vd  = Kd + (size_t)SEQ * DIM;                // [DIM][SEQ]  (V^T)
  _Float16* Od  = Vd + (size_t)SEQ * DIM;                // [SEQ][DIM]

  conv_x<<<(SEQ * DIM) / 1024, 256, 0, stream>>>(x, xh, SEQ * DIM);
  conv_wT4<<<dim3(32, 32, 4), 256, 0, stream>>>(Wq, Wk, Wv, Wo, WqT, WkT, WvT, WoT);

  gemm_qkv<<<dim3(SEQ / 64, DIM / 128, 3), 256, 0, stream>>>(
      xh, WqT, WkT, WvT, bq, bk, bv, Qd, Kd, Vd);

  attn_fwd<<<dim3(SEQ / 128, NH), 256, 0, stream>>>(Qd, Kd, Vd, Od);

  gemm_out<<<dim3(SEQ / 64, DIM / 128), 256, 0, stream>>>(Od, WoT, bo, (float*)d_out);
}